// Round 6
// baseline (1326.768 us; speedup 1.0000x reference)
//
#include <hip/hip_runtime.h>
#include <math.h>

#define NN 50000
#define EE 800000
#define EPS 1e-5f
#define SCAN_CH 196   // ceil(NN/256)

#define NEG_BIG (-1e30f)
#define RESCALE_THR 4.0f

#define LO_SCALE 2048.0f       // 2^11 exponent shift for the f16 lo plane
#define LO_INV   (1.0f/2048.0f)

typedef unsigned short u16;
typedef _Float16 f16x8 __attribute__((ext_vector_type(8)));
typedef float f32x4 __attribute__((ext_vector_type(4)));

__device__ __forceinline__ u16 f2h(float f) {
    _Float16 h = (_Float16)f;               // v_cvt_f16_f32, RNE
    return __builtin_bit_cast(u16, h);
}
__device__ __forceinline__ float h2f(u16 u) {
    return (float)__builtin_bit_cast(_Float16, u);
}

// quad (4-lane) and octet (8-lane) DPP reductions — pure VALU, no LDS
__device__ __forceinline__ float dpp_add4(float x) {
    int t;
    t = __builtin_amdgcn_update_dpp(0, __float_as_int(x), 0xB1, 0xf, 0xf, true);
    x += __int_as_float(t);
    t = __builtin_amdgcn_update_dpp(0, __float_as_int(x), 0x4E, 0xf, 0xf, true);
    x += __int_as_float(t);
    return x;
}
__device__ __forceinline__ float dpp_add8(float x) {
    int t;
    t = __builtin_amdgcn_update_dpp(0, __float_as_int(x), 0xB1, 0xf, 0xf, true);
    x += __int_as_float(t);
    t = __builtin_amdgcn_update_dpp(0, __float_as_int(x), 0x4E, 0xf, 0xf, true);
    x += __int_as_float(t);
    t = __builtin_amdgcn_update_dpp(0, __float_as_int(x), 0x141, 0xf, 0xf, true);
    x += __int_as_float(t);
    return x;
}

// ---------------------------------------------------------------------------
// CSR build: histogram -> 3-kernel parallel scan -> scatter (packs src+ea)
// ---------------------------------------------------------------------------
__global__ void hist_kernel(const int* __restrict__ dst, int* cnt) {
    int e = blockIdx.x * blockDim.x + threadIdx.x;
    if (e < EE) atomicAdd(&cnt[dst[e]], 1);
}

__global__ void scan_part(const int* __restrict__ cnt, int* __restrict__ part) {
    __shared__ int red[256];
    int b = blockIdx.x, t = threadIdx.x;
    int i = b * SCAN_CH + t;
    int v = (t < SCAN_CH && i < NN) ? cnt[i] : 0;
    red[t] = v;
    __syncthreads();
#pragma unroll
    for (int s = 128; s; s >>= 1) {
        if (t < s) red[t] += red[t + s];
        __syncthreads();
    }
    if (t == 0) part[b] = red[0];
}

__global__ void scan_block(int* part) {
    __shared__ int buf[2][256];
    int t = threadIdx.x;
    int v = part[t];
    int p = 0;
    buf[0][t] = v;
    __syncthreads();
#pragma unroll
    for (int off = 1; off < 256; off <<= 1) {
        buf[p ^ 1][t] = buf[p][t] + ((t >= off) ? buf[p][t - off] : 0);
        __syncthreads();
        p ^= 1;
    }
    part[t] = buf[p][t] - v;
}

__global__ void scan_final(int* __restrict__ cntcur, const int* __restrict__ part,
                           int* __restrict__ row_start) {
    __shared__ int buf[2][256];
    int b = blockIdx.x, t = threadIdx.x;
    int i = b * SCAN_CH + t;
    int v = (t < SCAN_CH && i < NN) ? cntcur[i] : 0;
    int p = 0;
    buf[0][t] = v;
    __syncthreads();
#pragma unroll
    for (int off = 1; off < 256; off <<= 1) {
        buf[p ^ 1][t] = buf[p][t] + ((t >= off) ? buf[p][t - off] : 0);
        __syncthreads();
        p ^= 1;
    }
    if (t < SCAN_CH && i < NN) {
        int pos = part[b] + buf[p][t] - v;   // exclusive
        row_start[i] = pos;
        cntcur[i] = pos;                     // scatter cursor
    }
    if (b == 0 && t == 0) row_start[NN] = EE;
}

__global__ void scatter_kernel(const int* __restrict__ ei, const float* __restrict__ ea,
                               int* cursor, int2* __restrict__ edge_pack) {
    int e = blockIdx.x * blockDim.x + threadIdx.x;
    if (e < EE) {
        int d = ei[EE + e];
        int pos = atomicAdd(&cursor[d], 1);
        edge_pack[pos] = make_int2(ei[e], __float_as_int(ea[e]));
    }
}

// ---------------------------------------------------------------------------
// fp32 -> f16 hi + scaled-lo split of a dense array (vectorized), n4 = elems/4
// ---------------------------------------------------------------------------
__global__ void split_f32(const float* __restrict__ in, u16* __restrict__ hi,
                          u16* __restrict__ lo, int n4) {
    int i = blockIdx.x * blockDim.x + threadIdx.x;
    if (i >= n4) return;
    float4 v = ((const float4*)in)[i];
    ushort4 h, l;
    h.x = f2h(v.x); l.x = f2h((v.x - h2f(h.x)) * LO_SCALE);
    h.y = f2h(v.y); l.y = f2h((v.y - h2f(h.y)) * LO_SCALE);
    h.z = f2h(v.z); l.z = f2h((v.z - h2f(h.z)) * LO_SCALE);
    h.w = f2h(v.w); l.w = f2h((v.w - h2f(h.w)) * LO_SCALE);
    ((ushort4*)hi)[i] = h;
    ((ushort4*)lo)[i] = l;
}

// ---------------------------------------------------------------------------
// Weight convert: 9 layers of [Wl|Wr] -> Wt[layer][256][128] f16 hi/lo.
// ---------------------------------------------------------------------------
__global__ void conv_w(const float* __restrict__ l1Wl, const float* __restrict__ l1Wr,
                       const float* __restrict__ midWl, const float* __restrict__ midWr,
                       u16* __restrict__ Wh, u16* __restrict__ Wlo) {
    int tid = blockIdx.x * 256 + threadIdx.x;
    if (tid >= 9 * 256 * 128) return;
    int L = tid >> 15;            // /32768
    int rem = tid & 32767;
    int n = rem >> 7, k = rem & 127;
    const float* WL;
    const float* WR;
    if (L == 0) { WL = l1Wl; WR = l1Wr; }
    else {
        WL = midWl + (size_t)(L - 1) * 16384;
        WR = midWr + (size_t)(L - 1) * 16384;
    }
    float w = (n < 128) ? WL[k * 128 + n] : WR[k * 128 + (n - 128)];
    u16 h = f2h(w);
    Wh[tid] = h;
    Wlo[tid] = f2h((w - h2f(h)) * LO_SCALE);
}

// ---------------------------------------------------------------------------
// MFMA f16 split GEMM. Output now in PLANES: C[plane][N][128], plane 0 = xl
// (Wl cols), plane 1 = xr (Wr cols). Structure = round 5 (B regs loop-
// invariant, 8 A row-tiles streamed with prefetch; verified absmax 1.0).
// ---------------------------------------------------------------------------
__global__ __launch_bounds__(256) void gemm_mfma(const u16* __restrict__ Ah,
                                                 const u16* __restrict__ Al,
                                                 const u16* __restrict__ Bh,
                                                 const u16* __restrict__ Bl,
                                                 float* __restrict__ C) {
    int w    = threadIdx.x >> 6;
    int lane = threadIdx.x & 63;
    int lr = lane & 15;
    int kg = lane >> 4;
    int rowbase = blockIdx.x * 128;
    int colb = w * 32;                      // col within the 128-wide plane
    int colbase = blockIdx.y * 128 + colb;  // col within Wt[256]

    // ---- B fragments: loop-invariant, held in registers (64 VGPR) ----
    f16x8 bh[2][4], bl[2][4];
#pragma unroll
    for (int ct = 0; ct < 2; ++ct) {
        size_t boff = (size_t)(colbase + ct * 16 + lr) * 128 + (size_t)(kg * 8);
#pragma unroll
        for (int ks = 0; ks < 4; ++ks) {
            bh[ct][ks] = *(const f16x8*)(Bh + boff + ks * 32);
            bl[ct][ks] = *(const f16x8*)(Bl + boff + ks * 32);
        }
    }

    auto aoff_of = [&](int rt) {
        int arow = rowbase + rt * 16 + lr;
        if (arow >= NN) arow = NN - 1;
        return (size_t)arow * 128 + (size_t)(kg * 8);
    };
    f16x8 ahc[4], alc[4], ahn[4], aln[4];
    {
        size_t ao = aoff_of(0);
#pragma unroll
        for (int ks = 0; ks < 4; ++ks) {
            ahc[ks] = *(const f16x8*)(Ah + ao + ks * 32);
            alc[ks] = *(const f16x8*)(Al + ao + ks * 32);
        }
    }

    float* Cp = C + (size_t)blockIdx.y * ((size_t)NN * 128);

#pragma unroll
    for (int rt = 0; rt < 8; ++rt) {
        if (rt < 7) {
            size_t ao = aoff_of(rt + 1);
#pragma unroll
            for (int ks = 0; ks < 4; ++ks) {
                ahn[ks] = *(const f16x8*)(Ah + ao + ks * 32);
                aln[ks] = *(const f16x8*)(Al + ao + ks * 32);
            }
        }

        f32x4 aH[2], aL[2];
#pragma unroll
        for (int ct = 0; ct < 2; ++ct) {
            aH[ct] = (f32x4){0.f, 0.f, 0.f, 0.f};
            aL[ct] = (f32x4){0.f, 0.f, 0.f, 0.f};
        }
#pragma unroll
        for (int ks = 0; ks < 4; ++ks) {
#pragma unroll
            for (int ct = 0; ct < 2; ++ct) {
                aH[ct] = __builtin_amdgcn_mfma_f32_16x16x32_f16(ahc[ks], bh[ct][ks], aH[ct], 0, 0, 0);
                aL[ct] = __builtin_amdgcn_mfma_f32_16x16x32_f16(alc[ks], bh[ct][ks], aL[ct], 0, 0, 0);
                aL[ct] = __builtin_amdgcn_mfma_f32_16x16x32_f16(ahc[ks], bl[ct][ks], aL[ct], 0, 0, 0);
            }
        }

        int crow0 = rowbase + rt * 16 + kg * 4;
#pragma unroll
        for (int ct = 0; ct < 2; ++ct) {
            float* cp = Cp + (size_t)crow0 * 128 + colb + ct * 16 + lr;
#pragma unroll
            for (int r = 0; r < 4; ++r) {
                if (crow0 + r < NN)
                    cp[(size_t)r * 128] = fmaf(aL[ct][r], LO_INV, aH[ct][r]);
            }
        }

        if (rt < 7) {
#pragma unroll
            for (int ks = 0; ks < 4; ++ks) { ahc[ks] = ahn[ks]; alc[ks] = aln[ks]; }
        }
    }
}

// ---------------------------------------------------------------------------
// Small fp32 GEMM for layer 10 (A stride 128, nc<=64)
// ---------------------------------------------------------------------------
__global__ __launch_bounds__(256) void gemm_tile(const float* __restrict__ A,
                                                 const float* __restrict__ B,
                                                 float* __restrict__ C,
                                                 int M, int nc, int ldb, int ldc, int coff) {
    __shared__ float As[128][64];
    __shared__ float Bs[128][64];
    int t  = threadIdx.x;
    int bm = blockIdx.x * 64;
    int bn = blockIdx.y * 64;
    {
        int k4 = (t & 31) << 2;
        int r0 = t >> 5;
#pragma unroll
        for (int pass = 0; pass < 8; ++pass) {
            int row = r0 + pass * 8;
            int gm  = bm + row;
            float4 v = make_float4(0.f, 0.f, 0.f, 0.f);
            if (gm < M) v = *(const float4*)(A + (size_t)gm * 128 + k4);
            As[k4 + 0][row] = v.x; As[k4 + 1][row] = v.y;
            As[k4 + 2][row] = v.z; As[k4 + 3][row] = v.w;
        }
    }
    {
        int c4 = (t & 15) << 2;
        int kr = t >> 4;
#pragma unroll
        for (int pass = 0; pass < 8; ++pass) {
            int k  = kr + pass * 16;
            int gc = bn + c4;
            float4 v = make_float4(0.f, 0.f, 0.f, 0.f);
            if (gc < nc) v = *(const float4*)(B + (size_t)k * ldb + gc);
            *(float4*)&Bs[k][c4] = v;
        }
    }
    __syncthreads();

    int tx = t & 15, ty = t >> 4;
    int m0 = ty * 4, c0 = tx * 4;
    float acc[4][4] = {{0.f}};
#pragma unroll 8
    for (int k = 0; k < 128; ++k) {
        float4 av = *(const float4*)&As[k][m0];
        float4 bv = *(const float4*)&Bs[k][c0];
        float a4[4] = {av.x, av.y, av.z, av.w};
        float b4[4] = {bv.x, bv.y, bv.z, bv.w};
#pragma unroll
        for (int i = 0; i < 4; ++i)
#pragma unroll
            for (int j = 0; j < 4; ++j) acc[i][j] = fmaf(a4[i], b4[j], acc[i][j]);
    }
#pragma unroll
    for (int i = 0; i < 4; ++i) {
        int gm = bm + m0 + i;
        int gc = bn + c0;
        if (gm < M && gc < nc) {
            *(float4*)(C + (size_t)gm * ldc + coff + gc) =
                make_float4(acc[i][0], acc[i][1], acc[i][2], acc[i][3]);
        }
    }
}

// ---------------------------------------------------------------------------
// Node kernel layers 1-9 (round-6): 16 lanes/edge, 8 ch/lane, 4 edge slots
// per wave (one wave per node). Quad-DPP head reduce (head = 32 ch = 4 lanes).
// Depth-1 register prefetch of next 4 edges. Defer-max online softmax with
// NEG_BIG annihilation (dead-slot garbage is zeroed by exp2(mx-M)=0 at merge).
// Reads compact xl plane [N][128] (halved L2 working set vs interleaved).
// ---------------------------------------------------------------------------
__global__ __launch_bounds__(256) void node_agg_128(const float* __restrict__ xlr,
                                                    const int* __restrict__ row_start,
                                                    const int2* __restrict__ epack,
                                                    const float* __restrict__ We,
                                                    const float* __restrict__ att,
                                                    const float* __restrict__ bias,
                                                    const float* __restrict__ bng,
                                                    const float* __restrict__ bnb,
                                                    const float* __restrict__ bnm,
                                                    const float* __restrict__ bnv,
                                                    u16* __restrict__ ahi,
                                                    u16* __restrict__ alo,
                                                    int wf32,
                                                    float* __restrict__ hout) {
    int wave = (blockIdx.x * blockDim.x + threadIdx.x) >> 6;
    int lane = threadIdx.x & 63;
    if (wave >= NN) return;
    int slot = lane >> 4;            // edge slot 0..3
    int c0   = (lane & 15) << 3;     // 8 channels per lane

    const float* xlp = xlr;                           // xl plane [N][128]
    const float* xrp = xlr + (size_t)NN * 128;        // xr plane [N][128]

    const float L2E = 1.44269504f;
    const float4 xr0 = *(const float4*)(xrp + (size_t)wave * 128 + c0);
    const float4 xr1 = *(const float4*)(xrp + (size_t)wave * 128 + c0 + 4);
    const float4 we0 = *(const float4*)(We + c0);
    const float4 we1 = *(const float4*)(We + c0 + 4);
    const float4 at0 = *(const float4*)(att + c0);
    const float4 at1 = *(const float4*)(att + c0 + 4);
    float4 a60, a61, a40, a41;
    a60.x = 0.6f * L2E * at0.x; a40.x = 0.4f * L2E * at0.x;
    a60.y = 0.6f * L2E * at0.y; a40.y = 0.4f * L2E * at0.y;
    a60.z = 0.6f * L2E * at0.z; a40.z = 0.4f * L2E * at0.z;
    a60.w = 0.6f * L2E * at0.w; a40.w = 0.4f * L2E * at0.w;
    a61.x = 0.6f * L2E * at1.x; a41.x = 0.4f * L2E * at1.x;
    a61.y = 0.6f * L2E * at1.y; a41.y = 0.4f * L2E * at1.y;
    a61.z = 0.6f * L2E * at1.z; a41.z = 0.4f * L2E * at1.z;
    a61.w = 0.6f * L2E * at1.w; a41.w = 0.4f * L2E * at1.w;

    int beg = row_start[wave], end = row_start[wave + 1];
    int lastE = end - 1;

    float mx = NEG_BIG, sm = 0.f;
    float4 aA = make_float4(0.f, 0.f, 0.f, 0.f);
    float4 aB = make_float4(0.f, 0.f, 0.f, 0.f);

    auto score8 = [&](float eav, const float4& xa, const float4& xb) -> float {
        float m0 = xa.x + fmaf(eav, we0.x, xr0.x);
        float m1 = xa.y + fmaf(eav, we0.y, xr0.y);
        float m2 = xa.z + fmaf(eav, we0.z, xr0.z);
        float m3 = xa.w + fmaf(eav, we0.w, xr0.w);
        float m4 = xb.x + fmaf(eav, we1.x, xr1.x);
        float m5 = xb.y + fmaf(eav, we1.y, xr1.y);
        float m6 = xb.z + fmaf(eav, we1.z, xr1.z);
        float m7 = xb.w + fmaf(eav, we1.w, xr1.w);
        float p = fmaf(a60.x, m0, a40.x * fabsf(m0));
        p = fmaf(a60.y, m1, fmaf(a40.y, fabsf(m1), p));
        p = fmaf(a60.z, m2, fmaf(a40.z, fabsf(m2), p));
        p = fmaf(a60.w, m3, fmaf(a40.w, fabsf(m3), p));
        p = fmaf(a61.x, m4, fmaf(a41.x, fabsf(m4), p));
        p = fmaf(a61.y, m5, fmaf(a41.y, fabsf(m5), p));
        p = fmaf(a61.z, m6, fmaf(a41.z, fabsf(m6), p));
        p = fmaf(a61.w, m7, fmaf(a41.w, fabsf(m7), p));
        return dpp_add4(p);   // head = 32 ch = one aligned 4-lane quad
    };

    auto upd = [&](float p, const float4& xa, const float4& xb) {
        float d = p - mx;
        if (__ballot(d > RESCALE_THR)) {        // rare wave-uniform slow path
            float nm = fmaxf(mx, p);
            float sc = exp2f(mx - nm);
            float w  = exp2f(p - nm);
            sm = fmaf(sm, sc, w);
            aA.x = fmaf(aA.x, sc, w * xa.x); aA.y = fmaf(aA.y, sc, w * xa.y);
            aA.z = fmaf(aA.z, sc, w * xa.z); aA.w = fmaf(aA.w, sc, w * xa.w);
            aB.x = fmaf(aB.x, sc, w * xb.x); aB.y = fmaf(aB.y, sc, w * xb.y);
            aB.z = fmaf(aB.z, sc, w * xb.z); aB.w = fmaf(aB.w, sc, w * xb.w);
            mx = nm;
        } else {
            float w = exp2f(d);
            sm += w;
            aA.x = fmaf(w, xa.x, aA.x); aA.y = fmaf(w, xa.y, aA.y);
            aA.z = fmaf(w, xa.z, aA.z); aA.w = fmaf(w, xa.w, aA.w);
            aB.x = fmaf(w, xb.x, aB.x); aB.y = fmaf(w, xb.y, aB.y);
            aB.z = fmaf(w, xb.z, aB.z); aB.w = fmaf(w, xb.w, aB.w);
        }
    };

    int nE = end - beg;
    int last4 = beg + (nE & ~3);

    // depth-1 prefetch pipeline, 4 edges (one per slot) per iteration
    int2 pkn; float4 xan, xbn;
    if (beg < last4) {
        pkn = epack[beg + slot];
        const float* rp = xlp + ((size_t)pkn.x << 7) + c0;
        xan = *(const float4*)rp;
        xbn = *(const float4*)(rp + 4);
    }
    for (int j = beg; j < last4; ) {
        int2 pk = pkn; float4 xa = xan, xb = xbn;
        j += 4;
        if (j < last4) {
            pkn = epack[j + slot];
            const float* rp = xlp + ((size_t)pkn.x << 7) + c0;
            xan = *(const float4*)rp;
            xbn = *(const float4*)(rp + 4);
        }
        float p = score8(__int_as_float(pk.y), xa, xb);
        upd(p, xa, xb);
    }
    if (last4 < end) {   // tail: 1..3 real edges; dead slots forced NEG_BIG
        int je = last4 + slot;
        bool dead = je > lastE; if (dead) je = lastE;
        int2 pk = epack[je];
        const float* rp = xlp + ((size_t)pk.x << 7) + c0;
        float4 xa = *(const float4*)rp;
        float4 xb = *(const float4*)(rp + 4);
        float p = score8(__int_as_float(pk.y), xa, xb);
        p = dead ? NEG_BIG : p;
        upd(p, xa, xb);
    }

    // merge the 4 slot-states (lanes l, l^16, l^32, l^48 share channels)
#pragma unroll
    for (int off = 16; off <= 32; off <<= 1) {
        float  Mo  = __shfl_xor(mx, off);
        float  smo = __shfl_xor(sm, off);
        float4 aAo, aBo;
        aAo.x = __shfl_xor(aA.x, off); aAo.y = __shfl_xor(aA.y, off);
        aAo.z = __shfl_xor(aA.z, off); aAo.w = __shfl_xor(aA.w, off);
        aBo.x = __shfl_xor(aB.x, off); aBo.y = __shfl_xor(aB.y, off);
        aBo.z = __shfl_xor(aB.z, off); aBo.w = __shfl_xor(aB.w, off);
        float Mn = fmaxf(mx, Mo);
        float ss = exp2f(mx - Mn), so = exp2f(Mo - Mn);
        sm = fmaf(sm, ss, smo * so);
        aA.x = fmaf(aA.x, ss, aAo.x * so); aA.y = fmaf(aA.y, ss, aAo.y * so);
        aA.z = fmaf(aA.z, ss, aAo.z * so); aA.w = fmaf(aA.w, ss, aAo.w * so);
        aB.x = fmaf(aB.x, ss, aBo.x * so); aB.y = fmaf(aB.y, ss, aBo.y * so);
        aB.z = fmaf(aB.z, ss, aBo.z * so); aB.w = fmaf(aB.w, ss, aBo.w * so);
        mx = Mn;
    }

    if (slot == 0) {   // lanes 0-15 cover all 128 channels (8 each)
        float inv = 1.f / (sm + 1e-16f);
        const float4 b0 = *(const float4*)(bias + c0);
        const float4 b1 = *(const float4*)(bias + c0 + 4);
        const float4 g0 = *(const float4*)(bng + c0);
        const float4 g1 = *(const float4*)(bng + c0 + 4);
        const float4 q0 = *(const float4*)(bnb + c0);
        const float4 q1 = *(const float4*)(bnb + c0 + 4);
        const float4 m0 = *(const float4*)(bnm + c0);
        const float4 m1 = *(const float4*)(bnm + c0 + 4);
        const float4 v0 = *(const float4*)(bnv + c0);
        const float4 v1 = *(const float4*)(bnv + c0 + 4);
        float4 yA, yB;
        yA.x = fmaxf(fmaf(aA.x, inv, b0.x), 0.f);
        yA.y = fmaxf(fmaf(aA.y, inv, b0.y), 0.f);
        yA.z = fmaxf(fmaf(aA.z, inv, b0.z), 0.f);
        yA.w = fmaxf(fmaf(aA.w, inv, b0.w), 0.f);
        yB.x = fmaxf(fmaf(aB.x, inv, b1.x), 0.f);
        yB.y = fmaxf(fmaf(aB.y, inv, b1.y), 0.f);
        yB.z = fmaxf(fmaf(aB.z, inv, b1.z), 0.f);
        yB.w = fmaxf(fmaf(aB.w, inv, b1.w), 0.f);
        yA.x = (yA.x - m0.x) * rsqrtf(v0.x + EPS) * g0.x + q0.x;
        yA.y = (yA.y - m0.y) * rsqrtf(v0.y + EPS) * g0.y + q0.y;
        yA.z = (yA.z - m0.z) * rsqrtf(v0.z + EPS) * g0.z + q0.z;
        yA.w = (yA.w - m0.w) * rsqrtf(v0.w + EPS) * g0.w + q0.w;
        yB.x = (yB.x - m1.x) * rsqrtf(v1.x + EPS) * g1.x + q1.x;
        yB.y = (yB.y - m1.y) * rsqrtf(v1.y + EPS) * g1.y + q1.y;
        yB.z = (yB.z - m1.z) * rsqrtf(v1.z + EPS) * g1.z + q1.z;
        yB.w = (yB.w - m1.w) * rsqrtf(v1.w + EPS) * g1.w + q1.w;

        ushort4 hA, lA, hB, lB;
        hA.x = f2h(yA.x); lA.x = f2h((yA.x - h2f(hA.x)) * LO_SCALE);
        hA.y = f2h(yA.y); lA.y = f2h((yA.y - h2f(hA.y)) * LO_SCALE);
        hA.z = f2h(yA.z); lA.z = f2h((yA.z - h2f(hA.z)) * LO_SCALE);
        hA.w = f2h(yA.w); lA.w = f2h((yA.w - h2f(hA.w)) * LO_SCALE);
        hB.x = f2h(yB.x); lB.x = f2h((yB.x - h2f(hB.x)) * LO_SCALE);
        hB.y = f2h(yB.y); lB.y = f2h((yB.y - h2f(hB.y)) * LO_SCALE);
        hB.z = f2h(yB.z); lB.z = f2h((yB.z - h2f(hB.z)) * LO_SCALE);
        hB.w = f2h(yB.w); lB.w = f2h((yB.w - h2f(hB.w)) * LO_SCALE);
        *(ushort4*)(ahi + (size_t)wave * 128 + c0)     = hA;
        *(ushort4*)(ahi + (size_t)wave * 128 + c0 + 4) = hB;
        *(ushort4*)(alo + (size_t)wave * 128 + c0)     = lA;
        *(ushort4*)(alo + (size_t)wave * 128 + c0 + 4) = lB;
        if (wf32) {
            *(float4*)(hout + (size_t)wave * 128 + c0)     = yA;
            *(float4*)(hout + (size_t)wave * 128 + c0 + 4) = yB;
        }
    }
}

// ---------------------------------------------------------------------------
// Layer 10 (round-6 rewrite, same template): half-wave per node, 8 lanes/edge
// x 4 ch/lane (C=32, H=1), 4 edge slots per half, float4 gathers, dpp_add8
// head reduce, defer-max, slot merge via shfl_xor 8/16. Fused linear output.
// ---------------------------------------------------------------------------
__global__ __launch_bounds__(256) void node_agg_l10(const float* __restrict__ xlr,
                                                    const int* __restrict__ row_start,
                                                    const int2* __restrict__ epack,
                                                    const float* __restrict__ We,
                                                    const float* __restrict__ att,
                                                    const float* __restrict__ bias,
                                                    const float* __restrict__ bng,
                                                    const float* __restrict__ bnb,
                                                    const float* __restrict__ bnm,
                                                    const float* __restrict__ bnv,
                                                    const float* __restrict__ linW,
                                                    const float* __restrict__ linb,
                                                    float* __restrict__ out) {
    int n = (blockIdx.x * blockDim.x + threadIdx.x) >> 5;
    if (n >= NN) return;
    int q    = threadIdx.x & 31;
    int slot = q >> 3;              // edge slot 0..3 within the half-wave
    int c0   = (q & 7) << 2;        // 4 channels of 32

    const float L2E = 1.44269504f;
    const float4 xr = *(const float4*)(xlr + (size_t)n * 64 + 32 + c0);
    const float4 we = *(const float4*)(We + c0);
    const float4 at = *(const float4*)(att + c0);
    float4 a6, a4;
    a6.x = 0.6f * L2E * at.x; a4.x = 0.4f * L2E * at.x;
    a6.y = 0.6f * L2E * at.y; a4.y = 0.4f * L2E * at.y;
    a6.z = 0.6f * L2E * at.z; a4.z = 0.4f * L2E * at.z;
    a6.w = 0.6f * L2E * at.w; a4.w = 0.4f * L2E * at.w;

    int beg = row_start[n], end = row_start[n + 1];
    int lastE = end - 1;

    float mx = NEG_BIG, sm = 0.f;
    float4 ac = make_float4(0.f, 0.f, 0.f, 0.f);

    auto score4 = [&](float eav, const float4& xv) -> float {
        float m0 = xv.x + fmaf(eav, we.x, xr.x);
        float m1 = xv.y + fmaf(eav, we.y, xr.y);
        float m2 = xv.z + fmaf(eav, we.z, xr.z);
        float m3 = xv.w + fmaf(eav, we.w, xr.w);
        float p = fmaf(a6.x, m0, a4.x * fabsf(m0));
        p = fmaf(a6.y, m1, fmaf(a4.y, fabsf(m1), p));
        p = fmaf(a6.z, m2, fmaf(a4.z, fabsf(m2), p));
        p = fmaf(a6.w, m3, fmaf(a4.w, fabsf(m3), p));
        return dpp_add8(p);     // 32 ch = aligned 8-lane group
    };

    auto upd = [&](float p, const float4& xv) {
        float d = p - mx;
        if (__ballot(d > RESCALE_THR)) {
            float nm = fmaxf(mx, p);
            float sc = exp2f(mx - nm);
            float w  = exp2f(p - nm);
            sm = fmaf(sm, sc, w);
            ac.x = fmaf(ac.x, sc, w * xv.x); ac.y = fmaf(ac.y, sc, w * xv.y);
            ac.z = fmaf(ac.z, sc, w * xv.z); ac.w = fmaf(ac.w, sc, w * xv.w);
            mx = nm;
        } else {
            float w = exp2f(d);
            sm += w;
            ac.x = fmaf(w, xv.x, ac.x); ac.y = fmaf(w, xv.y, ac.y);
            ac.z = fmaf(w, xv.z, ac.z); ac.w = fmaf(w, xv.w, ac.w);
        }
    };

    int nE = end - beg;
    int last4 = beg + (nE & ~3);

    int2 pkn; float4 xvn;
    if (beg < last4) {
        pkn = epack[beg + slot];
        xvn = *(const float4*)(xlr + ((size_t)pkn.x << 6) + c0);
    }
    for (int j = beg; j < last4; ) {
        int2 pk = pkn; float4 xv = xvn;
        j += 4;
        if (j < last4) {
            pkn = epack[j + slot];
            xvn = *(const float4*)(xlr + ((size_t)pkn.x << 6) + c0);
        }
        float p = score4(__int_as_float(pk.y), xv);
        upd(p, xv);
    }
    if (last4 < end) {
        int je = last4 + slot;
        bool dead = je > lastE; if (dead) je = lastE;
        int2 pk = epack[je];
        float4 xv = *(const float4*)(xlr + ((size_t)pk.x << 6) + c0);
        float p = score4(__int_as_float(pk.y), xv);
        p = dead ? NEG_BIG : p;
        upd(p, xv);
    }

    // merge 4 slot-states within the half (shfl_xor 8 then 16; bit5 untouched)
#pragma unroll
    for (int off = 8; off <= 16; off <<= 1) {
        float  Mo  = __shfl_xor(mx, off);
        float  smo = __shfl_xor(sm, off);
        float4 aco;
        aco.x = __shfl_xor(ac.x, off); aco.y = __shfl_xor(ac.y, off);
        aco.z = __shfl_xor(ac.z, off); aco.w = __shfl_xor(ac.w, off);
        float Mn = fmaxf(mx, Mo);
        float ss = exp2f(mx - Mn), so = exp2f(Mo - Mn);
        sm = fmaf(sm, ss, smo * so);
        ac.x = fmaf(ac.x, ss, aco.x * so); ac.y = fmaf(ac.y, ss, aco.y * so);
        ac.z = fmaf(ac.z, ss, aco.z * so); ac.w = fmaf(ac.w, ss, aco.w * so);
        mx = Mn;
    }

    float inv = 1.f / (sm + 1e-16f);
    const float4 b4 = *(const float4*)(bias + c0);
    const float4 g4 = *(const float4*)(bng + c0);
    const float4 q4 = *(const float4*)(bnb + c0);
    const float4 m4 = *(const float4*)(bnm + c0);
    const float4 v4 = *(const float4*)(bnv + c0);
    float4 y;
    y.x = fmaxf(fmaf(ac.x, inv, b4.x), 0.f);
    y.y = fmaxf(fmaf(ac.y, inv, b4.y), 0.f);
    y.z = fmaxf(fmaf(ac.z, inv, b4.z), 0.f);
    y.w = fmaxf(fmaf(ac.w, inv, b4.w), 0.f);
    y.x = (y.x - m4.x) * rsqrtf(v4.x + EPS) * g4.x + q4.x;
    y.y = (y.y - m4.y) * rsqrtf(v4.y + EPS) * g4.y + q4.y;
    y.z = (y.z - m4.z) * rsqrtf(v4.z + EPS) * g4.z + q4.z;
    y.w = (y.w - m4.w) * rsqrtf(v4.w + EPS) * g4.w + q4.w;

    // fused linear: t[k] = sum_c y_c * linW[c][k]; per-lane 4 rows of linW
    const float4 w0 = *(const float4*)(linW + (c0 + 0) * 4);
    const float4 w1 = *(const float4*)(linW + (c0 + 1) * 4);
    const float4 w2 = *(const float4*)(linW + (c0 + 2) * 4);
    const float4 w3 = *(const float4*)(linW + (c0 + 3) * 4);
    float4 t;
    t.x = fmaf(y.x, w0.x, fmaf(y.y, w1.x, fmaf(y.z, w2.x, y.w * w3.x)));
    t.y = fmaf(y.x, w0.y, fmaf(y.y, w1.y, fmaf(y.z, w2.y, y.w * w3.y)));
    t.z = fmaf(y.x, w0.z, fmaf(y.y, w1.z, fmaf(y.z, w2.z, y.w * w3.z)));
    t.w = fmaf(y.x, w0.w, fmaf(y.y, w1.w, fmaf(y.z, w2.w, y.w * w3.w)));
    t.x = dpp_add8(t.x); t.y = dpp_add8(t.y);
    t.z = dpp_add8(t.z); t.w = dpp_add8(t.w);

    if (q == 0) {
        const float4 lb = *(const float4*)linb;
        float4 o;
        o.x = t.x + lb.x; o.y = t.y + lb.y; o.z = t.z + lb.z; o.w = t.w + lb.w;
        *(float4*)(out + (size_t)n * 4) = o;
    }
}

// ---------------------------------------------------------------------------
extern "C" void kernel_launch(void* const* d_in, const int* in_sizes, int n_in,
                              void* d_out, int out_size, void* d_ws, size_t ws_size,
                              hipStream_t stream) {
    const float* x      = (const float*)d_in[0];
    const int*   ei     = (const int*)d_in[1];
    const float* ea     = (const float*)d_in[2];
    const float* l1_Wl  = (const float*)d_in[3];
    const float* l1_Wr  = (const float*)d_in[4];
    const float* l1_We  = (const float*)d_in[5];
    const float* l1_att = (const float*)d_in[6];
    const float* l1_b   = (const float*)d_in[7];
    const float* mid_Wl = (const float*)d_in[8];
    const float* mid_Wr = (const float*)d_in[9];
    const float* mid_We = (const float*)d_in[10];
    const float* mid_att= (const float*)d_in[11];
    const float* mid_b  = (const float*)d_in[12];
    const float* l10_Wl = (const float*)d_in[13];
    const float* l10_Wr = (const float*)d_in[14];
    const float* l10_We = (const float*)d_in[15];
    const float* l10_att= (const float*)d_in[16];
    const float* l10_b  = (const float*)d_in[17];
    const float* bn_g   = (const float*)d_in[18];
    const float* bn_b   = (const float*)d_in[19];
    const float* bn_m   = (const float*)d_in[20];
    const float* bn_v   = (const float*)d_in[21];
    const float* bn10_g = (const float*)d_in[22];
    const float* bn10_b = (const float*)d_in[23];
    const float* bn10_m = (const float*)d_in[24];
    const float* bn10_v = (const float*)d_in[25];
    const float* lin_W  = (const float*)d_in[26];
    const float* lin_b  = (const float*)d_in[27];

    char* ws = (char*)d_ws;
    auto take = [&](size_t bytes) { char* p = ws; ws += (bytes + 255) & ~size_t(255); return p; };
    int*   row_start  = (int*)  take(sizeof(int) * (NN + 1));
    int*   cursor     = (int*)  take(sizeof(int) * NN);
    int*   part       = (int*)  take(sizeof(int) * 256);
    int2*  epack      = (int2*) take(sizeof(int2) * EE);
    float* xlr        = (float*)take(sizeof(float) * (size_t)NN * 256);
    float* h0         = (float*)take(sizeof(float) * (size_t)NN * 128);
    u16*   Ahi        = (u16*)  take(sizeof(u16) * (size_t)NN * 128);
    u16*   Alo        = (u16*)  take(sizeof(u16) * (size_t)NN * 128);
    u16*   Wthi       = (u16*)  take(sizeof(u16) * 9 * 256 * 128);
    u16*   Wtlo       = (u16*)  take(sizeof(u16) * 9 * 256 * 128);

    // --- CSR build ---
    hipMemsetAsync(cursor, 0, sizeof(int) * NN, stream);
    hist_kernel<<<EE / 256, 256, 0, stream>>>(ei + EE, cursor);
    scan_part<<<256, 256, 0, stream>>>(cursor, part);
    scan_block<<<1, 256, 0, stream>>>(part);
    scan_final<<<256, 256, 0, stream>>>(cursor, part, row_start);
    scatter_kernel<<<EE / 256, 256, 0, stream>>>(ei, ea, cursor, epack);

    // --- one-time conversions ---
    split_f32<<<(NN * 128 / 4 + 255) / 256, 256, 0, stream>>>(x, Ahi, Alo, NN * 128 / 4);
    conv_w<<<(9 * 256 * 128 + 255) / 256, 256, 0, stream>>>(l1_Wl, l1_Wr, mid_Wl, mid_Wr,
                                                            Wthi, Wtlo);

    const int GBM = (NN + 127) / 128;  // 391 row-blocks
    dim3 gmm(GBM, 2);

    // --- layer 1 ---
    gemm_mfma<<<gmm, 256, 0, stream>>>(Ahi, Alo, Wthi, Wtlo, xlr);
    node_agg_128<<<(NN * 64) / 256, 256, 0, stream>>>(
        xlr, row_start, epack, l1_We, l1_att, l1_b,
        bn_g, bn_b, bn_m, bn_v, Ahi, Alo, 0, h0);

    // --- layers 2-9 ---
    for (int i = 0; i < 8; ++i) {
        gemm_mfma<<<gmm, 256, 0, stream>>>(Ahi, Alo,
                                           Wthi + (size_t)(i + 1) * 32768,
                                           Wtlo + (size_t)(i + 1) * 32768, xlr);
        node_agg_128<<<(NN * 64) / 256, 256, 0, stream>>>(
            xlr, row_start, epack,
            mid_We + (size_t)i * 128, mid_att + (size_t)i * 128, mid_b + (size_t)i * 128,
            bn_g + (size_t)(i + 1) * 128, bn_b + (size_t)(i + 1) * 128,
            bn_m + (size_t)(i + 1) * 128, bn_v + (size_t)(i + 1) * 128,
            Ahi, Alo, (i == 7) ? 1 : 0, h0);
    }

    // --- layer 10 (xlr reused as [N][64]) ---
    const int MB = (NN + 63) / 64;  // 782
    dim3 g1(MB, 1);
    gemm_tile<<<g1, 256, 0, stream>>>(h0, l10_Wl, xlr, NN, 32, 32, 64, 0);
    gemm_tile<<<g1, 256, 0, stream>>>(h0, l10_Wr, xlr, NN, 32, 32, 64, 32);
    node_agg_l10<<<(NN * 32 + 255) / 256, 256, 0, stream>>>(
        xlr, row_start, epack, l10_We, l10_att, l10_b,
        bn10_g, bn10_b, bn10_m, bn10_v, lin_W, lin_b, (float*)d_out);
}